// Round 3
// baseline (711.889 us; speedup 1.0000x reference)
//
#include <hip/hip_runtime.h>
#include <math.h>

#define D_MODEL 4096
#define NEXP    64
#define TOPK    8
#define NTOK    16384      // 4 * 4096
#define BLK_TOK 64
#define DC      64
#define NCHUNK  (D_MODEL / DC)   // 64

// ws layout: [0, 256K) floats = WT[4096][64]; then int flags[16384]
#define WT_FLOATS (D_MODEL * NEXP)

// Kernel 0: W[64][4096] -> WT[4096][64] (1 MB, L2-hot)
__global__ void transpose_w_kernel(const float* __restrict__ W, float* __restrict__ WT) {
    int idx = blockIdx.x * 256 + threadIdx.x;   // 262144 elements
    int d = idx >> 6;
    int e = idx & 63;
    WT[idx] = W[e * D_MODEL + d];
}

__global__ __launch_bounds__(256)
void router_kernel(const float* __restrict__ x, const float* __restrict__ WT,
                   float* __restrict__ out_w, float* __restrict__ out_i,
                   float* __restrict__ out_p, int* __restrict__ flags) {
    __shared__ float lds_x[2][DC][BLK_TOK];   // [buf][d][tok]  16 KB each
    __shared__ float lds_w[2][DC][NEXP];      // [buf][d][e]    16 KB each

    const int tid  = threadIdx.x;
    const int tok0 = blockIdx.x * BLK_TOK;

    // compute mapping: 8 expert-cols x 32 token-rows, 2 tokens x 8 experts per thread
    const int ecol = tid & 7;
    const int trow = tid >> 3;
    const int e0   = ecol * 8;
    const int t0   = trow * 2;

    // staging mapping
    const int srow = tid >> 2;   // 0..63 (token row for x-stage)
    const int sf4  = tid & 3;    // 0..3

    float acc[2][8];
#pragma unroll
    for (int t = 0; t < 2; ++t)
#pragma unroll
        for (int e = 0; e < 8; ++e) acc[t][e] = 0.f;

    float4 xr[4];   // x: 64 tok x 64 d = 4096 floats = 256 thr * 4 float4
    float4 wr[4];   // W: 64 d x 64 e  = 4096 floats = 256 thr * 4 float4

    const float* xbase = x + (size_t)(tok0 + srow) * D_MODEL + sf4 * 4;

    auto load_chunk = [&](int d0) {
#pragma unroll
        for (int j = 0; j < 4; ++j)
            xr[j] = *(const float4*)(xbase + d0 + j * 16);
        const float* wsrc = WT + (size_t)d0 * NEXP;
#pragma unroll
        for (int j = 0; j < 4; ++j)
            wr[j] = *(const float4*)(wsrc + j * 1024 + tid * 4);   // lane-contiguous, coalesced
    };
    auto store_chunk = [&](int buf) {
#pragma unroll
        for (int j = 0; j < 4; ++j) {
            int dd = sf4 * 4 + j * 16;
            lds_x[buf][dd + 0][srow] = xr[j].x;
            lds_x[buf][dd + 1][srow] = xr[j].y;
            lds_x[buf][dd + 2][srow] = xr[j].z;
            lds_x[buf][dd + 3][srow] = xr[j].w;
        }
        float* wdst = &lds_w[buf][0][0];
#pragma unroll
        for (int j = 0; j < 4; ++j)
            *(float4*)(wdst + j * 1024 + tid * 4) = wr[j];         // linear, conflict-free
    };
    auto compute_chunk = [&](int buf) {
#pragma unroll 8
        for (int d = 0; d < DC; ++d) {
            const float2 xv = *(const float2*)&lds_x[buf][d][t0];
            const float4 w0 = *(const float4*)&lds_w[buf][d][e0];
            const float4 w1 = *(const float4*)&lds_w[buf][d][e0 + 4];
            acc[0][0] += xv.x * w0.x;  acc[1][0] += xv.y * w0.x;
            acc[0][1] += xv.x * w0.y;  acc[1][1] += xv.y * w0.y;
            acc[0][2] += xv.x * w0.z;  acc[1][2] += xv.y * w0.z;
            acc[0][3] += xv.x * w0.w;  acc[1][3] += xv.y * w0.w;
            acc[0][4] += xv.x * w1.x;  acc[1][4] += xv.y * w1.x;
            acc[0][5] += xv.x * w1.y;  acc[1][5] += xv.y * w1.y;
            acc[0][6] += xv.x * w1.z;  acc[1][6] += xv.y * w1.z;
            acc[0][7] += xv.x * w1.w;  acc[1][7] += xv.y * w1.w;
        }
    };

    // prologue
    load_chunk(0);
    store_chunk(0);
    __syncthreads();

    for (int k = 0; k < NCHUNK; ++k) {
        if (k + 1 < NCHUNK) load_chunk((k + 1) * DC);   // in flight during compute
        compute_chunk(k & 1);
        if (k + 1 < NCHUNK) store_chunk((k + 1) & 1);   // other buffer, no hazard
        __syncthreads();
    }

    // ---- fused epilogue ----
    // logits -> LDS, stride 65 (conflict-free row reads). 64*65 = 4160 floats <= 8192 avail.
    float* lg = &lds_x[0][0][0];
#pragma unroll
    for (int t = 0; t < 2; ++t)
#pragma unroll
        for (int e = 0; e < 8; ++e)
            lg[(t0 + t) * 65 + e0 + e] = acc[t][e];
    __syncthreads();

    if (tid < 64) {
        const int tok = tok0 + tid;
        float p[64];
        float m = -INFINITY;
#pragma unroll
        for (int e = 0; e < 64; ++e) {
            p[e] = lg[tid * 65 + e];
            m = fmaxf(m, p[e]);
        }
        float z = 0.f;
#pragma unroll
        for (int e = 0; e < 64; ++e) {
            p[e] = __expf(p[e] - m);
            z += p[e];
        }
        const float rz = 1.f / z;
#pragma unroll
        for (int e = 0; e < 64; ++e) p[e] *= rz;

        // write router_probs
#pragma unroll
        for (int e4 = 0; e4 < 16; ++e4) {
            float4 v = make_float4(p[e4 * 4], p[e4 * 4 + 1], p[e4 * 4 + 2], p[e4 * 4 + 3]);
            *(float4*)&out_p[(size_t)tok * NEXP + e4 * 4] = v;
        }

        // branch-free top-9 insertion (strict > keeps lowest index on ties, as lax.top_k)
        float tv[9]; int ti[9];
#pragma unroll
        for (int k = 0; k < 9; ++k) { tv[k] = -1.f; ti[k] = 0; }
        for (int e = 0; e < 64; ++e) {
            float v = p[e]; int idx = e;
#pragma unroll
            for (int k = 0; k < 9; ++k) {
                const bool gt = v > tv[k];
                const float nv = gt ? v : tv[k];
                const int   ni = gt ? idx : ti[k];
                const float ov = gt ? tv[k] : v;
                const int   oi = gt ? ti[k] : idx;
                tv[k] = nv; ti[k] = ni; v = ov; idx = oi;
            }
        }
        // ambiguity flag: any adjacent gap among ranks 1..9 below 2e-4 relative
        // (fp32 accum error sigma ~ 2.7e-6 in logit space => 74-sigma margin)
        int flag = 0;
#pragma unroll
        for (int k = 0; k < 8; ++k)
            if (tv[k] - tv[k + 1] <= tv[k] * 2e-4f + 1e-12f) flag = 1;
        flags[tok] = flag;

        float s8 = 0.f;
#pragma unroll
        for (int k = 0; k < 8; ++k) s8 += tv[k];
        const float denom = s8 + 1e-9f;
#pragma unroll
        for (int k = 0; k < 8; ++k) {
            out_w[tok * TOPK + k] = tv[k] / denom;
            out_i[tok * TOPK + k] = (float)ti[k];   // tuple buffer read back as fp32
        }
    }
}

// Repair kernel: for flagged tokens, recompute logits in exact fp64 and rewrite
// out_w / out_i. (out_p from the fp32 pass is within threshold regardless.)
__global__ __launch_bounds__(64)
void repair_kernel(const float* __restrict__ x, const float* __restrict__ W,
                   const int* __restrict__ flags,
                   float* __restrict__ out_w, float* __restrict__ out_i) {
    const int tok = blockIdx.x;
    if (flags[tok] == 0) return;

    __shared__ float  xs[D_MODEL];   // 16 KB
    __shared__ double ls[NEXP];

    const int tid = threadIdx.x;     // 0..63 == expert id
    const float4* xsrc = (const float4*)(x + (size_t)tok * D_MODEL);
#pragma unroll 4
    for (int i = tid; i < D_MODEL / 4; i += 64)
        ((float4*)xs)[i] = xsrc[i];
    __syncthreads();

    const float* wrow = W + (size_t)tid * D_MODEL;   // L2-hot (1 MB total)
    double s0 = 0., s1 = 0., s2 = 0., s3 = 0.;
    for (int d = 0; d < D_MODEL; d += 4) {
        const float4 wv = *(const float4*)(wrow + d);
        const float4 xv = *(const float4*)(xs + d);
        s0 += (double)xv.x * (double)wv.x;
        s1 += (double)xv.y * (double)wv.y;
        s2 += (double)xv.z * (double)wv.z;
        s3 += (double)xv.w * (double)wv.w;
    }
    ls[tid] = (s0 + s1) + (s2 + s3);
    __syncthreads();

    if (tid == 0) {
        double m = -1e300;
        for (int e = 0; e < 64; ++e) m = ls[e] > m ? ls[e] : m;
        double p[64], Z = 0.;
        for (int e = 0; e < 64; ++e) { p[e] = exp(ls[e] - m); Z += p[e]; }
        for (int e = 0; e < 64; ++e) p[e] /= Z;

        double tv[8]; int ti[8];
        for (int k = 0; k < 8; ++k) { tv[k] = -1.; ti[k] = 0; }
        for (int e = 0; e < 64; ++e) {
            double v = p[e]; int idx = e;
            for (int k = 0; k < 8; ++k) {
                const bool gt = v > tv[k];
                const double nv = gt ? v : tv[k];
                const int    ni = gt ? idx : ti[k];
                const double ov = gt ? tv[k] : v;
                const int    oi = gt ? ti[k] : idx;
                tv[k] = nv; ti[k] = ni; v = ov; idx = oi;
            }
        }
        double s8 = 0.;
        for (int k = 0; k < 8; ++k) s8 += tv[k];
        const double denom = s8 + 1e-9;
        for (int k = 0; k < 8; ++k) {
            out_w[tok * TOPK + k] = (float)(tv[k] / denom);
            out_i[tok * TOPK + k] = (float)ti[k];
        }
    }
}

extern "C" void kernel_launch(void* const* d_in, const int* in_sizes, int n_in,
                              void* d_out, int out_size, void* d_ws, size_t ws_size,
                              hipStream_t stream) {
    const float* x = (const float*)d_in[0];   // [4,4096,4096]
    const float* W = (const float*)d_in[1];   // [64,4096]
    float* WT   = (float*)d_ws;               // [4096,64], 1 MB scratch
    int*  flags = (int*)((float*)d_ws + WT_FLOATS);   // [16384]
    float* out   = (float*)d_out;
    float* out_w = out;                       // [16384,8]
    float* out_i = out + NTOK * TOPK;         // [16384,8] (as float)
    float* out_p = out + 2 * NTOK * TOPK;     // [16384,64]

    transpose_w_kernel<<<(D_MODEL * NEXP) / 256, 256, 0, stream>>>(W, WT);
    router_kernel<<<NTOK / BLK_TOK, 256, 0, stream>>>(x, WT, out_w, out_i, out_p, flags);
    repair_kernel<<<NTOK, 64, 0, stream>>>(x, W, flags, out_w, out_i);
}

// Round 4
// 660.650 us; speedup vs baseline: 1.0776x; 1.0776x over previous
//
#include <hip/hip_runtime.h>
#include <math.h>

#define D_MODEL 4096
#define NEXP    64
#define TOPK    8
#define NTOK    16384      // 4 * 4096
#define BLK_TOK 64
#define DC      128        // d per chunk
#define NCHUNK  (D_MODEL / DC)   // 32

#define WT2_FLOATS (NEXP * D_MODEL)   // 262144 floats = 1 MB

// WT2 layout: [g:8][d:4096][j:8] where WT2[g][d][j] = W[g*8+j][d].
// A wave owning expert-group g reads 32 consecutive floats per 4 d -> s_load_dwordx16 x2.
__global__ void transpose_w_kernel(const float* __restrict__ W, float* __restrict__ WT2) {
    int o = blockIdx.x * 256 + threadIdx.x;    // 262144 total
    int j = o & 7;
    int d = (o >> 3) & (D_MODEL - 1);
    int g = o >> 15;
    WT2[o] = W[(size_t)(g * 8 + j) * D_MODEL + d];
}

__global__ __launch_bounds__(512)
void router_kernel(const float* __restrict__ x, const float* __restrict__ WT2,
                   float* __restrict__ out_w, float* __restrict__ out_i,
                   float* __restrict__ out_p, int* __restrict__ cnt,
                   int* __restrict__ list) {
    // x tile, interleaved: [buf][d/4][tok][4] -> lane reads b128 (4 d) at canonical stride-16B
    __shared__ float lds_x[2][DC / 4][BLK_TOK][4];   // 64 KB

    const int tid  = threadIdx.x;
    const int lane = tid & 63;                                   // token within block
    const int g    = __builtin_amdgcn_readfirstlane(tid >> 6);   // wave id == expert group
    const int tok0 = blockIdx.x * BLK_TOK;

    // staging mapping: 64 rows (tokens) x 8 threads/row, 4 float4 each = 128 d
    const int row = tid >> 3;
    const int q   = tid & 7;

    float acc[8];
#pragma unroll
    for (int j = 0; j < 8; ++j) acc[j] = 0.f;

    float4 xr[4];
    const float* xbase = x + (size_t)(tok0 + row) * D_MODEL + q * 4;
    const float* wk    = WT2 + (g << 15);   // this wave's [4096][8] W slab (uniform addr)

    auto load_chunk = [&](int d0) {
#pragma unroll
        for (int j = 0; j < 4; ++j)
            xr[j] = *(const float4*)(xbase + d0 + j * 32);   // 64 lanes x 16B contiguous
    };
    auto store_chunk = [&](int buf) {
#pragma unroll
        for (int j = 0; j < 4; ++j)
            *(float4*)&lds_x[buf][q + j * 8][row][0] = xr[j];  // d4 = q + j*8
    };
    auto compute_chunk = [&](int buf, int k) {
        const float* wc = wk + k * DC * 8;               // uniform -> s_load
        const float* xl = &lds_x[buf][0][lane][0];
#pragma unroll 4
        for (int d4 = 0; d4 < DC / 4; ++d4) {
            const float4 xq = *(const float4*)(xl + d4 * (BLK_TOK * 4)); // ds_read_b128
            const float* wd = wc + d4 * 32;              // 32 consecutive floats (4d x 8e)
#pragma unroll
            for (int dd = 0; dd < 4; ++dd) {
                const float xv = (dd == 0) ? xq.x : (dd == 1) ? xq.y : (dd == 2) ? xq.z : xq.w;
#pragma unroll
                for (int j = 0; j < 8; ++j)
                    acc[j] = fmaf(xv, wd[dd * 8 + j], acc[j]);   // v_fmac v, s, v
            }
        }
    };

    // prologue
    load_chunk(0);
    store_chunk(0);
    __syncthreads();

    for (int k = 0; k < NCHUNK; ++k) {
        if (k + 1 < NCHUNK) load_chunk((k + 1) * DC);    // global loads in flight
        compute_chunk(k & 1, k);
        if (k + 1 < NCHUNK) store_chunk((k + 1) & 1);    // other buffer: no read hazard
        __syncthreads();                                  // one barrier per chunk
    }

    // ---- epilogue ----
    float* lg = (float*)lds_x;          // reuse as [64][65] logits/probs (16.6 KB)
#pragma unroll
    for (int j = 0; j < 8; ++j)
        lg[lane * 65 + g * 8 + j] = acc[j];
    __syncthreads();

    if (tid < 64) {                     // wave 0: one token per lane
        const int tok = tok0 + tid;
        float p[64];
        float m = -INFINITY;
#pragma unroll
        for (int e = 0; e < 64; ++e) {
            p[e] = lg[tid * 65 + e];
            m = fmaxf(m, p[e]);
        }
        float z = 0.f;
#pragma unroll
        for (int e = 0; e < 64; ++e) {
            p[e] = __expf(p[e] - m);
            z += p[e];
        }
        const float rz = 1.f / z;
#pragma unroll
        for (int e = 0; e < 64; ++e) {
            p[e] *= rz;
            lg[tid * 65 + e] = p[e];    // publish probs for cooperative store
        }

        // branch-free top-9 (strict > => lowest index on ties, matching lax.top_k)
        float tv[9]; int ti[9];
#pragma unroll
        for (int k = 0; k < 9; ++k) { tv[k] = -1.f; ti[k] = 0; }
        for (int e = 0; e < 64; ++e) {
            float v = p[e]; int idx = e;
#pragma unroll
            for (int k = 0; k < 9; ++k) {
                const bool gt = v > tv[k];
                const float nv = gt ? v : tv[k];
                const int   ni = gt ? idx : ti[k];
                const float ov = gt ? tv[k] : v;
                const int   oi = gt ? ti[k] : idx;
                tv[k] = nv; ti[k] = ni; v = ov; idx = oi;
            }
        }
        // ambiguity flag: adjacent relative gap below 2e-4 (fp32 err sigma ~3e-6 => 66x margin)
        int flag = 0;
#pragma unroll
        for (int k = 0; k < 8; ++k)
            if (tv[k] - tv[k + 1] <= tv[k] * 2e-4f + 1e-12f) flag = 1;
        if (flag) {
            int s = atomicAdd(cnt, 1);
            list[s] = tok;
        }

        float s8 = 0.f;
#pragma unroll
        for (int k = 0; k < 8; ++k) s8 += tv[k];
        const float denom = s8 + 1e-9f;
#pragma unroll
        for (int k = 0; k < 8; ++k) {
            out_w[tok * TOPK + k] = tv[k] / denom;
            out_i[tok * TOPK + k] = (float)ti[k];
        }
    }
    __syncthreads();

    // cooperative coalesced probs store: 64 tok x 16 float4 = 1024 float4
    for (int i = tid; i < BLK_TOK * 16; i += 512) {
        const int t  = i >> 4;
        const int e4 = (i & 15) << 2;
        const float* src = &lg[t * 65 + e4];
        float4 v = make_float4(src[0], src[1], src[2], src[3]);
        *(float4*)&out_p[(size_t)(tok0 + t) * NEXP + e4] = v;
    }
}

// Repair: iterate compacted flagged-token list, recompute logits in fp64, rewrite w/i.
__global__ __launch_bounds__(64)
void repair_kernel(const float* __restrict__ x, const float* __restrict__ W,
                   const int* __restrict__ cnt, const int* __restrict__ list,
                   float* __restrict__ out_w, float* __restrict__ out_i) {
    __shared__ float  xs[D_MODEL];   // 16 KB
    __shared__ double ls[NEXP];
    const int tid = threadIdx.x;     // 0..63 == expert
    const int n   = cnt[0];

    for (int i = blockIdx.x; i < n; i += gridDim.x) {
        const int tok = list[i];
        __syncthreads();             // protect xs reuse across iterations
        const float4* xsrc = (const float4*)(x + (size_t)tok * D_MODEL);
        for (int v = tid; v < D_MODEL / 4; v += 64)
            ((float4*)xs)[v] = xsrc[v];
        __syncthreads();

        const float* wrow = W + (size_t)tid * D_MODEL;   // L2-hot
        double s0 = 0., s1 = 0., s2 = 0., s3 = 0.;
        for (int d = 0; d < D_MODEL; d += 4) {
            const float4 wv = *(const float4*)(wrow + d);
            const float4 xv = *(const float4*)(xs + d);
            s0 += (double)xv.x * (double)wv.x;
            s1 += (double)xv.y * (double)wv.y;
            s2 += (double)xv.z * (double)wv.z;
            s3 += (double)xv.w * (double)wv.w;
        }
        ls[tid] = (s0 + s1) + (s2 + s3);
        __syncthreads();

        if (tid == 0) {
            double m = -1e300;
            for (int e = 0; e < 64; ++e) m = ls[e] > m ? ls[e] : m;
            double p[64], Z = 0.;
            for (int e = 0; e < 64; ++e) { p[e] = exp(ls[e] - m); Z += p[e]; }
            for (int e = 0; e < 64; ++e) p[e] /= Z;

            double tv[8]; int ti[8];
            for (int k = 0; k < 8; ++k) { tv[k] = -1.; ti[k] = 0; }
            for (int e = 0; e < 64; ++e) {
                double v = p[e]; int idx = e;
                for (int k = 0; k < 8; ++k) {
                    const bool gt = v > tv[k];
                    const double nv = gt ? v : tv[k];
                    const int    ni = gt ? idx : ti[k];
                    const double ov = gt ? tv[k] : v;
                    const int    oi = gt ? ti[k] : idx;
                    tv[k] = nv; ti[k] = ni; v = ov; idx = oi;
                }
            }
            double s8 = 0.;
            for (int k = 0; k < 8; ++k) s8 += tv[k];
            const double denom = s8 + 1e-9;
            for (int k = 0; k < 8; ++k) {
                out_w[tok * TOPK + k] = (float)(tv[k] / denom);
                out_i[tok * TOPK + k] = (float)ti[k];
            }
        }
    }
}

extern "C" void kernel_launch(void* const* d_in, const int* in_sizes, int n_in,
                              void* d_out, int out_size, void* d_ws, size_t ws_size,
                              hipStream_t stream) {
    const float* x = (const float*)d_in[0];   // [4,4096,4096]
    const float* W = (const float*)d_in[1];   // [64,4096]

    float* WT2  = (float*)d_ws;                          // 1 MB
    int*   cnt  = (int*)((float*)d_ws + WT2_FLOATS);     // 1 int
    int*   list = cnt + 1;                               // up to 16384 ints

    float* out   = (float*)d_out;
    float* out_w = out;                       // [16384,8]
    float* out_i = out + NTOK * TOPK;         // [16384,8] (as float)
    float* out_p = out + 2 * NTOK * TOPK;     // [16384,64]

    hipMemsetAsync(cnt, 0, sizeof(int), stream);
    transpose_w_kernel<<<(WT2_FLOATS) / 256, 256, 0, stream>>>(W, WT2);
    router_kernel<<<NTOK / BLK_TOK, 512, 0, stream>>>(x, WT2, out_w, out_i, out_p, cnt, list);
    repair_kernel<<<256, 64, 0, stream>>>(x, W, cnt, list, out_w, out_i);
}